// Round 7
// baseline (228.012 us; speedup 1.0000x reference)
//
#include <hip/hip_runtime.h>

// Problem constants
#define BB 4
#define SS 2048
#define DD 512
#define HH 8
#define DKK 64
#define HDK 512   // H*DK

typedef __attribute__((ext_vector_type(4))) float f32x4;
typedef __attribute__((ext_vector_type(8))) __bf16 bf16x8;
typedef __attribute__((ext_vector_type(4))) __bf16 bf16x4;

#define MFMA16(a, b, c) __builtin_amdgcn_mfma_f32_16x16x32_bf16((a), (b), (c), 0, 0, 0)

#define GLOAD_LDS16(gptr, lptr)                                                    \
    __builtin_amdgcn_global_load_lds(                                              \
        (const __attribute__((address_space(1))) void*)(gptr),                     \
        (__attribute__((address_space(3))) void*)(lptr), 16, 0, 0)

__device__ inline bf16x8 cvt48(const f32x4 f0, const f32x4 f1) {
    bf16x8 w;
    w[0] = (__bf16)f0[0]; w[1] = (__bf16)f0[1]; w[2] = (__bf16)f0[2]; w[3] = (__bf16)f0[3];
    w[4] = (__bf16)f1[0]; w[5] = (__bf16)f1[1]; w[6] = (__bf16)f1[2]; w[7] = (__bf16)f1[3];
    return w;
}

// ---------------------------------------------------------------------------
// Kernel 1: projection GEMM, 128x128 tile, BK=32, double-buffered gload_lds
// pipeline (stage next || compute cur, one barrier per step).
//   z=0 -> qh [B,H,S,DK], z=1 -> kh [B,H,S,DK], z=2 -> vt [B,H,DK,S]
// ---------------------------------------------------------------------------
__global__ __launch_bounds__(256) void proj_kernel(
    const float* __restrict__ q, const float* __restrict__ k, const float* __restrict__ v,
    const float* __restrict__ Wq, const float* __restrict__ bq,
    __bf16* __restrict__ qh, __bf16* __restrict__ kh, __bf16* __restrict__ vt)
{
    const int z  = blockIdx.z;
    const float* X = (z == 0) ? q : (z == 1) ? k : v;
    const int m0 = blockIdx.x * 128;
    const int n0 = blockIdx.y * 128;

    __shared__ __align__(16) float As0[128 * 32], Bs0[128 * 32];  // 16 KB each
    __shared__ __align__(16) float As1[128 * 32], Bs1[128 * 32];  // dbuf: 64 KB total

    const int t    = threadIdx.x;
    const int lane = t & 63, wid = t >> 6;
    const int lo   = lane & 15, hi = lane >> 4;
    const int wm   = wid >> 1, wn = wid & 1;

    // staging: rows are 128 B (32 fp32). 1 DMA = 8 rows. wave w covers rows
    // [32w,32w+32) via 4 DMAs. lane -> row r0+(lane>>3), src chunk
    // (lane&7)^(row&7); row&7 == (lane>>3) (r0 multiple of 8).
    const int lrow = lane >> 3;                                // 0..7
    const int lchk = ((lane & 7) ^ lrow) << 4;                 // pre-swizzled src chunk
    const char* aSrc = (const char*)(X  + (size_t)(m0 + 32 * wid + lrow) * DD) + lchk;
    const char* bSrc = (const char*)(Wq + (size_t)(n0 + 32 * wid + lrow) * DD) + lchk;

    f32x4 acc[4][4] = {};

    auto stage = [&](float* Ab, float* Bb, int tt) {
#pragma unroll
        for (int i = 0; i < 4; ++i) {
            GLOAD_LDS16(aSrc + (size_t)i * (8 * DD * 4) + (size_t)tt * 128,
                        (char*)Ab + (32 * wid + 8 * i) * 128);
            GLOAD_LDS16(bSrc + (size_t)i * (8 * DD * 4) + (size_t)tt * 128,
                        (char*)Bb + (32 * wid + 8 * i) * 128);
        }
    };
    auto compute = [&](const float* Ab, const float* Bb) {
        bf16x8 a[4], b[4];
#pragma unroll
        for (int mi = 0; mi < 4; ++mi) {
            const int ar = wm * 64 + mi * 16 + lo;
            const int sw = (ar & 7) << 4;
            f32x4 f0 = *reinterpret_cast<const f32x4*>((const char*)Ab + ar * 128 + ((32 * hi) ^ sw));
            f32x4 f1 = *reinterpret_cast<const f32x4*>((const char*)Ab + ar * 128 + ((32 * hi + 16) ^ sw));
            a[mi] = cvt48(f0, f1);
        }
#pragma unroll
        for (int ni = 0; ni < 4; ++ni) {
            const int br = wn * 64 + ni * 16 + lo;
            const int sw = (br & 7) << 4;
            f32x4 f0 = *reinterpret_cast<const f32x4*>((const char*)Bb + br * 128 + ((32 * hi) ^ sw));
            f32x4 f1 = *reinterpret_cast<const f32x4*>((const char*)Bb + br * 128 + ((32 * hi + 16) ^ sw));
            b[ni] = cvt48(f0, f1);
        }
        __builtin_amdgcn_s_setprio(1);
#pragma unroll
        for (int mi = 0; mi < 4; ++mi)
#pragma unroll
            for (int ni = 0; ni < 4; ++ni)
                acc[mi][ni] = MFMA16(a[mi], b[ni], acc[mi][ni]);
        __builtin_amdgcn_s_setprio(0);
    };

    float *Ac = As0, *Bc = Bs0, *An = As1, *Bn = Bs1;
    stage(Ac, Bc, 0);
    __syncthreads();
    for (int tt = 0; tt < 16; ++tt) {
        if (tt < 15) stage(An, Bn, tt + 1);
        compute(Ac, Bc);
        __syncthreads();   // drains next stage's DMAs (hidden under compute) + syncs
        float* tmp;
        tmp = Ac; Ac = An; An = tmp;
        tmp = Bc; Bc = Bn; Bn = tmp;
    }

    // Epilogue: C/D col = lane&15 (n), row = 4*hi + r (m)
#pragma unroll
    for (int mi = 0; mi < 4; ++mi) {
#pragma unroll
        for (int ni = 0; ni < 4; ++ni) {
            const int n = n0 + wn * 64 + ni * 16 + lo;
            const float bias = bq[n];
            const int h_ = n >> 6, e_ = n & 63;
#pragma unroll
            for (int r = 0; r < 4; ++r) {
                const int m = m0 + wm * 64 + mi * 16 + hi * 4 + r;
                const float val = acc[mi][ni][r] + bias;
                const int b_ = m >> 11, s_ = m & (SS - 1);
                const size_t bh = (size_t)(b_ * HH + h_);
                if (z == 0)
                    qh[(bh * SS + s_) * DKK + e_] = (__bf16)val;
                else if (z == 1)
                    kh[(bh * SS + s_) * DKK + e_] = (__bf16)val;
                else
                    vt[(bh * DKK + e_) * SS + s_] = (__bf16)val;
            }
        }
    }
}

// ---------------------------------------------------------------------------
// Kernel 2: flash attention, swapped-QK^T, KV tile = 128, 16 q-rows/wave,
// 64 q-rows/block, defer-max (T13), reg-staged swizzled K/V LDS.
// ---------------------------------------------------------------------------
__global__ __launch_bounds__(256) void attn_kernel(
    const __bf16* __restrict__ qh, const __bf16* __restrict__ kh,
    const __bf16* __restrict__ vt, __bf16* __restrict__ concat)
{
    const int q0 = blockIdx.x * 64;
    const int bh = blockIdx.y;                 // b*H + h
    const int b_ = bh >> 3, h_ = bh & 7;
    const size_t base = (size_t)bh * SS * DKK;
    const __bf16* qhp = qh + base;
    const __bf16* khp = kh + base;
    const __bf16* vtp = vt + base;             // [DK][S] per (b,h)

    const int t    = threadIdx.x;
    const int lane = t & 63, wid = t >> 6;
    const int lo   = lane & 15, hi = lane >> 4;

    __shared__ __align__(16) __bf16 Ks[128 * 64];        // [kv][d] swizzled, 16 KB
    __shared__ __align__(16) __bf16 Vts[64 * 128];       // [e][kv] swizzled, 16 KB
    __shared__ __align__(16) __bf16 Ps[4][16][136];      // per-wave P [q][kv], 272 B rows

    char* KsB  = (char*)Ks;
    char* VtsB = (char*)Vts;
    char* PsB  = (char*)Ps + wid * (16 * 272) + lo * 272;

    // --- staging geometry (reg-staged; linear global chunk, XOR'd LDS chunk) ---
    // K: wave w stages rows [32w,32w+32): lane -> row 32w+8j+kr, chunk lane&7.
    const int kr = lane >> 3;                      // 0..7; row&7 == kr
    const int kc = (lane & 7) << 4;
    const char* kSrc = (const char*)khp + (size_t)(32 * wid + kr) * 128 + kc;
    const int   kDst = (32 * wid + kr) * 128 + (kc ^ (kr << 4));
    // V^T: wave w stages rows [16w,16w+16): lane -> row 16w+4j+vr, chunk lane&15.
    const int vr = lane >> 4;                      // 0..3
    const int vc = (lane & 15) << 4;
    const char* vSrc = (const char*)vtp + (size_t)(16 * wid + vr) * (SS * 2) + vc;

    // Q fragments (wave's 16 q-rows) in registers for the whole loop
    bf16x8 qf[2];
#pragma unroll
    for (int kk = 0; kk < 2; ++kk)
        qf[kk] = *reinterpret_cast<const bf16x8*>(
            &qhp[(size_t)(q0 + 16 * wid + lo) * DKK + 32 * kk + 8 * hi]);

    const int rsw = (lo & 7) << 4;                 // fragment-read swizzle (row&7 = lo&7)

    f32x4 acc[4] = {};
    float m_run = -INFINITY, l_run = 0.f;

    for (int tile = 0; tile < SS / 128; ++tile) {
        // issue global loads before the barrier (overlap prev PV)
        bf16x8 kreg[4], vreg[4];
#pragma unroll
        for (int j = 0; j < 4; ++j) {
            kreg[j] = *reinterpret_cast<const bf16x8*>(kSrc + j * (8 * 128));
            vreg[j] = *reinterpret_cast<const bf16x8*>(vSrc + (size_t)j * (4 * SS * 2));
        }
        kSrc += 128 * 128;   // +128 kv rows
        vSrc += 128 * 2;     // +128 kv cols

        __syncthreads();     // prev tile's LDS reads done
#pragma unroll
        for (int j = 0; j < 4; ++j) {
            *reinterpret_cast<bf16x8*>(KsB + kDst + j * (8 * 128)) = kreg[j];
            const int vrow = 16 * wid + 4 * j + vr;
            *reinterpret_cast<bf16x8*>(VtsB + vrow * 256 + (vc ^ ((vrow & 7) << 4))) = vreg[j];
        }
        __syncthreads();     // tiles visible

        // ---- scores: S^T[kv 128][q 16] via mfma(K, Q) ----
        f32x4 sc[8] = {};
        __builtin_amdgcn_s_setprio(1);
#pragma unroll
        for (int kk = 0; kk < 2; ++kk) {
            const int cb = (kk * 64 + 16 * hi) ^ rsw;
#pragma unroll
            for (int f = 0; f < 8; ++f) {
                bf16x8 kf = *reinterpret_cast<const bf16x8*>(KsB + (16 * f + lo) * 128 + cb);
                sc[f] = MFMA16(kf, qf[kk], sc[f]);
            }
        }
        __builtin_amdgcn_s_setprio(0);

        // ---- online softmax over 32 elements/lane (lane owns q = lo) ----
        {
            float mx = sc[0][0];
#pragma unroll
            for (int f = 0; f < 8; ++f)
#pragma unroll
                for (int r = 0; r < 4; ++r)
                    mx = fmaxf(mx, sc[f][r]);
            mx = fmaxf(mx, __shfl_xor(mx, 16));
            mx = fmaxf(mx, __shfl_xor(mx, 32));
            const float mxs = mx * 0.125f;
            if (!__all(mxs <= m_run + 8.0f)) {     // defer-max: rescale only on growth
                const float mnew = fmaxf(m_run, mxs);
                const float scl  = __expf(m_run - mnew);
                l_run *= scl;
#pragma unroll
                for (int f = 0; f < 4; ++f)
                    acc[f] *= scl;
                m_run = mnew;
            }
            float rs = 0.f;
#pragma unroll
            for (int f = 0; f < 8; ++f) {
                bf16x4 pk;
#pragma unroll
                for (int r = 0; r < 4; ++r) {
                    const float e = __expf(fmaf(sc[f][r], 0.125f, -m_run));
                    rs += e;
                    pk[r] = (__bf16)e;
                }
                *reinterpret_cast<bf16x4*>(PsB + 32 * f + 8 * hi) = pk;
            }
            rs += __shfl_xor(rs, 16);
            rs += __shfl_xor(rs, 32);
            l_run += rs;
        }
        // no block barrier: Ps is per-wave

        // ---- PV: O^T += mfma(V^T, P^T) over kv=128 (4 kks) ----
        __builtin_amdgcn_s_setprio(1);
#pragma unroll
        for (int kk = 0; kk < 4; ++kk) {
            bf16x8 pb = *reinterpret_cast<const bf16x8*>(PsB + 64 * kk + 16 * hi);
            const int cb = (kk * 64 + 16 * hi) ^ rsw;
#pragma unroll
            for (int f = 0; f < 4; ++f) {
                bf16x8 vf = *reinterpret_cast<const bf16x8*>(VtsB + (16 * f + lo) * 256 + cb);
                acc[f] = MFMA16(vf, pb, acc[f]);
            }
        }
        __builtin_amdgcn_s_setprio(0);
    }

    // ---- epilogue ----
    {
        const float inv = 1.0f / l_run;
        const int qrow = q0 + 16 * wid + lo;
        const size_t ob = ((size_t)b_ * SS + qrow) * HDK + h_ * DKK;
#pragma unroll
        for (int f = 0; f < 4; ++f) {
            bf16x4 o;
#pragma unroll
            for (int r = 0; r < 4; ++r)
                o[r] = (__bf16)(acc[f][r] * inv);
            *reinterpret_cast<bf16x4*>(&concat[ob + 16 * f + 4 * hi]) = o;
        }
    }
}

// ---------------------------------------------------------------------------
// Kernel 3: output projection. Tile 64(M)x128(N), BK=32, dbuf gload_lds
// pipeline. A = concat (bf16), B = Wout (fp32 -> cvt at read). Grid 512.
// ---------------------------------------------------------------------------
__global__ __launch_bounds__(256) void outproj_kernel(
    const __bf16* __restrict__ concat, const float* __restrict__ Wout,
    const float* __restrict__ bout, float* __restrict__ out)
{
    const int m0 = blockIdx.x * 64;
    const int n0 = blockIdx.y * 128;

    __shared__ __align__(16) __bf16 As0[64 * 32], As1[64 * 32];     // 4 KB each
    __shared__ __align__(16) float  Bs0[128 * 32], Bs1[128 * 32];   // 16 KB each

    const int t    = threadIdx.x;
    const int lane = t & 63, wid = t >> 6;
    const int lo   = lane & 15, hi = lane >> 4;
    const int wm   = wid >> 1, wn = wid & 1;

    // A staging: rows 64 B (32 bf16). 1 DMA = 16 rows; wave w -> rows [16w,16w+16).
    const int ar4  = lane >> 2;                                   // 0..15; row&3 = ar4&3
    const int achk = ((lane & 3) ^ (ar4 & 3)) << 4;
    const char* aSrc = (const char*)(concat + (size_t)(m0 + 16 * wid + ar4) * HDK) + achk;
    // B staging: rows 128 B (32 fp32). 4 DMAs/wave; wave w -> rows [32w,32w+32).
    const int br8  = lane >> 3;                                   // 0..7
    const int bchk = ((lane & 7) ^ br8) << 4;
    const char* bSrc = (const char*)(Wout + (size_t)(n0 + 32 * wid + br8) * HDK) + bchk;

    f32x4 acc[2][4] = {};

    auto stage = [&](__bf16* Ab, float* Bb, int tt) {
        GLOAD_LDS16(aSrc + (size_t)tt * 64, (char*)Ab + (16 * wid) * 64);
#pragma unroll
        for (int i = 0; i < 4; ++i)
            GLOAD_LDS16(bSrc + (size_t)i * (8 * HDK * 4) + (size_t)tt * 128,
                        (char*)Bb + (32 * wid + 8 * i) * 128);
    };
    auto compute = [&](const __bf16* Ab, const float* Bb) {
        bf16x8 a[2], b[4];
#pragma unroll
        for (int mi = 0; mi < 2; ++mi) {
            const int ar = wm * 32 + mi * 16 + lo;
            a[mi] = *reinterpret_cast<const bf16x8*>(
                (const char*)Ab + ar * 64 + ((16 * hi) ^ ((ar & 3) << 4)));
        }
#pragma unroll
        for (int ni = 0; ni < 4; ++ni) {
            const int br = wn * 64 + ni * 16 + lo;
            const int sw = (br & 7) << 4;
            f32x4 f0 = *reinterpret_cast<const f32x4*>((const char*)Bb + br * 128 + ((32 * hi) ^ sw));
            f32x4 f1 = *reinterpret_cast<const f32x4*>((const char*)Bb + br * 128 + ((32 * hi + 16) ^ sw));
            b[ni] = cvt48(f0, f1);
        }
        __builtin_amdgcn_s_setprio(1);
#pragma unroll
        for (int mi = 0; mi < 2; ++mi)
#pragma unroll
            for (int ni = 0; ni < 4; ++ni)
                acc[mi][ni] = MFMA16(a[mi], b[ni], acc[mi][ni]);
        __builtin_amdgcn_s_setprio(0);
    };

    __bf16 *Ac = As0, *An = As1;
    float  *Bc = Bs0, *Bn = Bs1;
    stage(Ac, Bc, 0);
    __syncthreads();
    for (int tt = 0; tt < 16; ++tt) {
        if (tt < 15) stage(An, Bn, tt + 1);
        compute(Ac, Bc);
        __syncthreads();
        __bf16* ta = Ac; Ac = An; An = ta;
        float*  tb = Bc; Bc = Bn; Bn = tb;
    }

#pragma unroll
    for (int mi = 0; mi < 2; ++mi) {
#pragma unroll
        for (int ni = 0; ni < 4; ++ni) {
            const int n = n0 + wn * 64 + ni * 16 + lo;
            const float bias = bout[n];
#pragma unroll
            for (int r = 0; r < 4; ++r) {
                const int m = m0 + wm * 32 + mi * 16 + hi * 4 + r;
                out[(size_t)m * DD + n] = acc[mi][ni][r] + bias;
            }
        }
    }
}

// ---------------------------------------------------------------------------
extern "C" void kernel_launch(void* const* d_in, const int* in_sizes, int n_in,
                              void* d_out, int out_size, void* d_ws, size_t ws_size,
                              hipStream_t stream)
{
    (void)in_sizes; (void)n_in; (void)out_size; (void)ws_size;
    const float* q    = (const float*)d_in[0];
    const float* k    = (const float*)d_in[1];
    const float* v    = (const float*)d_in[2];
    const float* Wq   = (const float*)d_in[3];
    const float* bq   = (const float*)d_in[4];
    const float* Wout = (const float*)d_in[5];
    const float* bout = (const float*)d_in[6];
    float* out = (float*)d_out;

    char* ws = (char*)d_ws;
    __bf16* qh = (__bf16*)(ws);                      // 8 MiB  [B,H,S,DK]
    __bf16* kh = (__bf16*)(ws + (8u << 20));         // 8 MiB  [B,H,S,DK]
    __bf16* vt = (__bf16*)(ws + (16u << 20));        // 8 MiB  [B,H,DK,S]
    __bf16* cc = (__bf16*)(ws + (24u << 20));        // 8 MiB  [B,S,H*DK]

    proj_kernel<<<dim3(BB * SS / 128, HDK / 128, 3), 256, 0, stream>>>(q, k, v, Wq, bq, qh, kh, vt);
    attn_kernel<<<dim3(SS / 64, BB * HH), 256, 0, stream>>>(qh, kh, vt, cc);
    outproj_kernel<<<dim3(BB * SS / 64, DD / 128), 256, 0, stream>>>(cc, Wout, bout, out);
}